// Round 1
// baseline (1382.313 us; speedup 1.0000x reference)
//
#include <hip/hip_runtime.h>

#define NN 50000
#define NE 1600000
#define DD 64

// -------- Kernel 1: COO SpMM scatter: hi[row[e],:] += val[e] * x[col[e],:]
// thread t -> edge e = t/16, float4-group f4 = t%16.
// 16 consecutive threads read one x row (256B) coalesced.
__global__ __launch_bounds__(256) void spmm_scatter(
    const float* __restrict__ x,
    const float* __restrict__ vals,
    const int* __restrict__ erow,
    const int* __restrict__ ecol,
    float* __restrict__ hi)
{
    long long t = (long long)blockIdx.x * blockDim.x + threadIdx.x;
    if (t >= (long long)NE * 16) return;
    int e  = (int)(t >> 4);
    int f4 = (int)(t & 15);
    int r = erow[e];
    int c = ecol[e];
    float v = vals[e];
    float4 xv = *reinterpret_cast<const float4*>(x + (long long)c * DD + f4 * 4);
    float* dst = hi + (long long)r * DD + f4 * 4;
    unsafeAtomicAdd(dst + 0, v * xv.x);
    unsafeAtomicAdd(dst + 1, v * xv.y);
    unsafeAtomicAdd(dst + 2, v * xv.z);
    unsafeAtomicAdd(dst + 3, v * xv.w);
}

// -------- Kernel 2: out = support @ (theta*W + (1-theta)*I),
// support = (1-s)*hi + s*h0. One thread per row, W' staged in LDS.
__global__ __launch_bounds__(256) void fused_gemm(
    const float* __restrict__ hi,
    const float* __restrict__ h0,
    const float* __restrict__ W,
    const float* __restrict__ lamda,
    const float* __restrict__ s_ptr,
    const int* __restrict__ l_ptr,
    float* __restrict__ out)
{
    __shared__ float Wp[DD * DD];

    float theta = lamda[0] / (float)l_ptr[0];
    float s     = s_ptr[0];

    // stage W' = theta*W + (1-theta)*I
    for (int i = threadIdx.x; i < DD * DD; i += 256) {
        int k = i >> 6, j = i & 63;
        float wv = theta * W[i];
        if (k == j) wv += (1.0f - theta);
        Wp[i] = wv;
    }
    __syncthreads();

    int r = blockIdx.x * blockDim.x + threadIdx.x;
    if (r >= NN) return;

    // build support row in registers (plain float array, constant indices only)
    float sup[DD];
    {
        const float4* hi4 = reinterpret_cast<const float4*>(hi + (long long)r * DD);
        const float4* h04 = reinterpret_cast<const float4*>(h0 + (long long)r * DD);
        float oms = 1.0f - s;
        #pragma unroll
        for (int i = 0; i < 16; ++i) {
            float4 a = hi4[i];
            float4 b = h04[i];
            sup[i * 4 + 0] = oms * a.x + s * b.x;
            sup[i * 4 + 1] = oms * a.y + s * b.y;
            sup[i * 4 + 2] = oms * a.z + s * b.z;
            sup[i * 4 + 3] = oms * a.w + s * b.w;
        }
    }

    float acc[DD];
    #pragma unroll
    for (int j = 0; j < DD; ++j) acc[j] = 0.0f;

    #pragma unroll
    for (int k = 0; k < DD; ++k) {
        float sk = sup[k];
        #pragma unroll
        for (int j4 = 0; j4 < 16; ++j4) {
            float4 w = *reinterpret_cast<const float4*>(&Wp[k * DD + j4 * 4]);
            acc[j4 * 4 + 0] = fmaf(sk, w.x, acc[j4 * 4 + 0]);
            acc[j4 * 4 + 1] = fmaf(sk, w.y, acc[j4 * 4 + 1]);
            acc[j4 * 4 + 2] = fmaf(sk, w.z, acc[j4 * 4 + 2]);
            acc[j4 * 4 + 3] = fmaf(sk, w.w, acc[j4 * 4 + 3]);
        }
    }

    float4* out4 = reinterpret_cast<float4*>(out + (long long)r * DD);
    #pragma unroll
    for (int j4 = 0; j4 < 16; ++j4) {
        out4[j4] = make_float4(acc[j4 * 4 + 0], acc[j4 * 4 + 1],
                               acc[j4 * 4 + 2], acc[j4 * 4 + 3]);
    }
}

extern "C" void kernel_launch(void* const* d_in, const int* in_sizes, int n_in,
                              void* d_out, int out_size, void* d_ws, size_t ws_size,
                              hipStream_t stream) {
    const float* x     = (const float*)d_in[0];
    const float* h0    = (const float*)d_in[1];
    const float* evals = (const float*)d_in[2];
    const float* W     = (const float*)d_in[3];
    const int*   erow  = (const int*)d_in[4];
    const int*   ecol  = (const int*)d_in[5];
    const float* lamda = (const float*)d_in[6];
    const float* s_ptr = (const float*)d_in[7];
    const int*   l_ptr = (const int*)d_in[8];
    float* out = (float*)d_out;

    float* hi = (float*)d_ws;  // N*D floats = 12.8 MB scratch

    // zero the accumulator every call (harness does NOT re-poison between replays)
    hipMemsetAsync(hi, 0, (size_t)NN * DD * sizeof(float), stream);

    {
        long long total = (long long)NE * 16;
        int block = 256;
        long long grid = (total + block - 1) / block;
        spmm_scatter<<<(int)grid, block, 0, stream>>>(x, evals, erow, ecol, hi);
    }
    {
        int block = 256;
        int grid = (NN + block - 1) / block;
        fused_gemm<<<grid, block, 0, stream>>>(hi, h0, W, lamda, s_ptr, l_ptr, out);
    }
}

// Round 2
// 367.895 us; speedup vs baseline: 3.7574x; 3.7574x over previous
//
#include <hip/hip_runtime.h>

#define NN 50000
#define NE 1600000
#define DD 64

// ---------- K1: histogram of edge rows (int atomics, L2-absorbed) ----------
__global__ __launch_bounds__(256) void hist_rows(
    const int* __restrict__ erow, int* __restrict__ cnt)
{
    int e = blockIdx.x * 256 + threadIdx.x;
    if (e < NE) atomicAdd(&cnt[erow[e]], 1);
}

// ---------- K2: exclusive scan of 50k counts, in place (single block) ------
__global__ __launch_bounds__(1024) void scan_counts(int* __restrict__ cnt)
{
    __shared__ int part[1024];
    const int CH = 49;                  // 1024*49 = 50176 >= NN
    int t = threadIdx.x;
    int base = t * CH;

    int sum = 0;
    for (int i = 0; i < CH; ++i) {
        int idx = base + i;
        if (idx < NN) sum += cnt[idx];
    }
    part[t] = sum;
    __syncthreads();

    // inclusive Hillis-Steele over 1024 partials
    for (int off = 1; off < 1024; off <<= 1) {
        int v = (t >= off) ? part[t - off] : 0;
        __syncthreads();
        part[t] += v;
        __syncthreads();
    }

    int run = part[t] - sum;            // exclusive prefix for this chunk
    for (int i = 0; i < CH; ++i) {
        int idx = base + i;
        if (idx < NN) { int c = cnt[idx]; cnt[idx] = run; run += c; }
    }
}

// ---------- K3: scatter edges into row-sorted order ------------------------
// After this kernel, cursor[r] == end offset of row r (start = cursor[r-1]).
__global__ __launch_bounds__(256) void scatter_edges(
    const int* __restrict__ erow, const int* __restrict__ ecol,
    const float* __restrict__ evals,
    int* __restrict__ cursor, int* __restrict__ scol, float* __restrict__ sval)
{
    int e = blockIdx.x * 256 + threadIdx.x;
    if (e >= NE) return;
    int r = erow[e];
    int p = atomicAdd(&cursor[r], 1);
    scol[p] = ecol[e];
    sval[p] = evals[e];
}

// ---------- K4: fused gather-SpMM + support mix + GEMM ----------------------
// 16 lanes per row (each lane owns 4 output cols). No atomics.
// out = ((1-s)*A@x + s*h0) @ (theta*W + (1-theta)*I)
__global__ __launch_bounds__(256) void spmm_gemm(
    const float* __restrict__ x,  const float* __restrict__ h0,
    const float* __restrict__ W,  const float* __restrict__ lamda,
    const float* __restrict__ s_ptr, const int* __restrict__ l_ptr,
    const int* __restrict__ cursor, const int* __restrict__ scol,
    const float* __restrict__ sval, float* __restrict__ out)
{
    __shared__ float Wp[DD * DD];       // 16 KB: W' = theta*W + (1-theta)*I

    float theta = lamda[0] / (float)l_ptr[0];
    float s     = s_ptr[0];

    for (int i = threadIdx.x; i < DD * DD; i += 256) {
        int k = i >> 6, j = i & 63;
        float wv = theta * W[i];
        if (k == j) wv += (1.0f - theta);
        Wp[i] = wv;
    }
    __syncthreads();

    int g  = threadIdx.x >> 4;          // group 0..15 -> row within block
    int f4 = threadIdx.x & 15;          // float4 slot within row
    int r  = blockIdx.x * 16 + g;
    if (r >= NN) return;                // grid is exact (50000 = 3125*16)

    int start = (r == 0) ? 0 : cursor[r - 1];
    int end   = cursor[r];

    float4 acc = make_float4(0.f, 0.f, 0.f, 0.f);
    for (int e = start; e < end; ++e) {
        int   c = scol[e];              // same addr across the 16-lane group: broadcast
        float v = sval[e];
        float4 xv = *reinterpret_cast<const float4*>(x + (size_t)c * DD + f4 * 4);
        acc.x = fmaf(v, xv.x, acc.x);
        acc.y = fmaf(v, xv.y, acc.y);
        acc.z = fmaf(v, xv.z, acc.z);
        acc.w = fmaf(v, xv.w, acc.w);
    }

    float4 hb = *reinterpret_cast<const float4*>(h0 + (size_t)r * DD + f4 * 4);
    float oms = 1.0f - s;
    float4 sup;
    sup.x = oms * acc.x + s * hb.x;
    sup.y = oms * acc.y + s * hb.y;
    sup.z = oms * acc.z + s * hb.z;
    sup.w = oms * acc.w + s * hb.w;

    // GEMM row: o[j] = sum_k sup[k] * Wp[k][j]; sup[k] lives in lane
    // (lanebase + k/4), component k%4 — broadcast via wave shuffle.
    float4 o = make_float4(0.f, 0.f, 0.f, 0.f);
    int lanebase = threadIdx.x & 48;    // start lane of this group within the wave
    #pragma unroll
    for (int k = 0; k < DD; ++k) {
        float comp = ((k & 3) == 0) ? sup.x :
                     ((k & 3) == 1) ? sup.y :
                     ((k & 3) == 2) ? sup.z : sup.w;   // k is compile-time: no dyn index
        float sk = __shfl(comp, lanebase + (k >> 2), 64);
        float4 w = *reinterpret_cast<const float4*>(&Wp[k * DD + f4 * 4]);
        o.x = fmaf(sk, w.x, o.x);
        o.y = fmaf(sk, w.y, o.y);
        o.z = fmaf(sk, w.z, o.z);
        o.w = fmaf(sk, w.w, o.w);
    }

    *reinterpret_cast<float4*>(out + (size_t)r * DD + f4 * 4) = o;
}

extern "C" void kernel_launch(void* const* d_in, const int* in_sizes, int n_in,
                              void* d_out, int out_size, void* d_ws, size_t ws_size,
                              hipStream_t stream) {
    const float* x     = (const float*)d_in[0];
    const float* h0    = (const float*)d_in[1];
    const float* evals = (const float*)d_in[2];
    const float* W     = (const float*)d_in[3];
    const int*   erow  = (const int*)d_in[4];
    const int*   ecol  = (const int*)d_in[5];
    const float* lamda = (const float*)d_in[6];
    const float* s_ptr = (const float*)d_in[7];
    const int*   l_ptr = (const int*)d_in[8];
    float* out = (float*)d_out;

    // workspace layout (~13.0 MB)
    char* ws = (char*)d_ws;
    int*   cursor = (int*)ws;                               // NN ints (counts -> prefix -> ends)
    size_t off = ((size_t)NN * 4 + 255) & ~(size_t)255;     // 200192
    int*   scol = (int*)(ws + off);                         // NE ints
    float* sval = (float*)(ws + off + (size_t)NE * 4);      // NE floats

    hipMemsetAsync(cursor, 0, (size_t)NN * sizeof(int), stream);

    hist_rows<<<(NE + 255) / 256, 256, 0, stream>>>(erow, cursor);
    scan_counts<<<1, 1024, 0, stream>>>(cursor);
    scatter_edges<<<(NE + 255) / 256, 256, 0, stream>>>(erow, ecol, evals,
                                                        cursor, scol, sval);
    spmm_gemm<<<NN / 16, 256, 0, stream>>>(x, h0, W, lamda, s_ptr, l_ptr,
                                           cursor, scol, sval, out);
}